// Round 7
// baseline (355.844 us; speedup 1.0000x reference)
//
#include <hip/hip_runtime.h>
#include <hip/hip_cooperative_groups.h>

namespace cg = cooperative_groups;

using u16 = unsigned short;
using u32 = unsigned int;

// Problem constants: B=8, T=2048, C=1024
constexpr int Cdim  = 1024;
constexpr int Bn    = 8;
constexpr int Tn    = 2048;
constexpr int Mrows = Bn * Tn;          // 16384 rows in all GEMMs
constexpr int NCH   = 64;               // wkv chunks per chain
constexpr int CLEN  = Tn / NCH;         // 32 steps per chunk
constexpr int CP    = Cdim / 2;         // 512 channel-pairs

// ---------- bf16 helpers (bit-level, RNE) ----------
__device__ inline u16 f2bf(float x) {
    u32 u = __float_as_uint(x);
    u += 0x7fffu + ((u >> 16) & 1u);
    return (u16)(u >> 16);
}
__device__ inline float bf2f(u16 x) {
    return __uint_as_float(((u32)x) << 16);
}

// ---------- fp32 -> bf16 cast: X + 3 weights, ONE dispatch ----------
__global__ __launch_bounds__(256)
void cast_all(const float* __restrict__ x, const float* __restrict__ vw,
              const float* __restrict__ rw, const float* __restrict__ ow,
              u16* __restrict__ Xb, u16* __restrict__ Wvr, u16* __restrict__ Wo)
{
    const int b = blockIdx.x;
    const float4* src;
    ushort4*      dst;
    int i;
    if (b < 16384)      { src = (const float4*)x;  dst = (ushort4*)Xb;                i = b * 256 + threadIdx.x; }
    else if (b < 17408) { src = (const float4*)vw; dst = (ushort4*)Wvr;               i = (b - 16384) * 256 + threadIdx.x; }
    else if (b < 18432) { src = (const float4*)rw; dst = (ushort4*)(Wvr + 1048576);   i = (b - 17408) * 256 + threadIdx.x; }
    else                { src = (const float4*)ow; dst = (ushort4*)Wo;                i = (b - 18432) * 256 + threadIdx.x; }
    float4 v = src[i];
    ushort4 o;
    o.x = f2bf(v.x); o.y = f2bf(v.y); o.z = f2bf(v.z); o.w = f2bf(v.w);
    dst[i] = o;
}

// ---------- MFMA bf16 NT-GEMM, 256x256 tile, 8-phase pipelined ----------
typedef __bf16 bf16x8 __attribute__((ext_vector_type(8)));
typedef float  f32x4  __attribute__((ext_vector_type(4)));

#define SB0() __builtin_amdgcn_sched_barrier(0)
#define BARRIER() do { SB0(); __builtin_amdgcn_s_barrier(); SB0(); } while (0)
#define LGKM0()   do { asm volatile("s_waitcnt lgkmcnt(0)" ::: "memory"); SB0(); } while (0)
#define VMW(n)    do { asm volatile("s_waitcnt vmcnt(" #n ")" ::: "memory"); SB0(); } while (0)

__device__ __forceinline__ void gload16(const u16* g, char* l) {
    __builtin_amdgcn_global_load_lds(
        (const __attribute__((address_space(1))) void*)g,
        (__attribute__((address_space(3))) void*)l, 16, 0, 0);
}

// One C-quadrant x K=64: 16 MFMAs, setprio-wrapped (T5).
template<int IB, int JB>
__device__ __forceinline__ void mma_quad(f32x4 (&acc)[8][4],
                                         const bf16x8 (&aF)[4][2],
                                         const bf16x8 (&bF)[4][2]) {
    __builtin_amdgcn_s_setprio(1);
    #pragma unroll
    for (int i = 0; i < 4; ++i)
        #pragma unroll
        for (int j = 0; j < 2; ++j) {
            acc[IB + i][JB + j] = __builtin_amdgcn_mfma_f32_16x16x32_bf16(
                aF[i][0], bF[JB + j][0], acc[IB + i][JB + j], 0, 0, 0);
            acc[IB + i][JB + j] = __builtin_amdgcn_mfma_f32_16x16x32_bf16(
                aF[i][1], bF[JB + j][1], acc[IB + i][JB + j], 0, 0, 0);
        }
    __builtin_amdgcn_s_setprio(0);
}

// Staging order matches CONSUMPTION order (all B quarters + A.l1 needed at
// ph1, A.l2 at ph3). Per-tile issue: bq0,bq1,bq2 | bq3,a.h0l1,a.h1l1 |
// a.h0l2,a.h1l2 | (none). Waits: VMW(6) at ph2 retires A.l2(t) (3-phase
// cover); VMW(2) at ph4 retires the 6 loads ph1(t+1) reads (>=2-phase cover).
__device__ __forceinline__ void stageB3(const u16* bG, int k0, char* nDst) {
    gload16(bG + k0,              nDst + 32768);
    gload16(bG +  64 * Cdim + k0, nDst + 32768 + 8192);
    gload16(bG + 128 * Cdim + k0, nDst + 32768 + 16384);
}
__device__ __forceinline__ void stageB1A2(const u16* bG, const u16* aG, int k0, char* nDst) {
    gload16(bG + 192 * Cdim + k0, nDst + 32768 + 24576);
    gload16(aG + k0,              nDst);
    gload16(aG + 128 * Cdim + k0, nDst + 16384);
}
__device__ __forceinline__ void stageA2(const u16* aG, int k0, char* nDst) {
    gload16(aG +  64 * Cdim + k0, nDst + 8192);
    gload16(aG + 192 * Cdim + k0, nDst + 24576);
}
__device__ __forceinline__ void stage_full(const u16* aG, const u16* bG, char* dst) {
    stageB3(bG, 0, dst);
    stageB1A2(bG, aG, 0, dst);
    stageA2(aG, 0, dst);
}

// K-loop over 16 K-tiles (15 staged + tail). Caller must have issued
// stage_full into buf0 and executed VMW(2); BARRIER (a.l2 loads may remain
// in flight -- retired by ph2's VMW(6) at t=0).
__device__ __forceinline__ void kloop(const u16* __restrict__ aG,
                                      const u16* __restrict__ bG,
                                      char* stDst, const char* aRd,
                                      const char* bRd, int x0,
                                      f32x4 (&acc)[8][4])
{
    bf16x8 aF[4][2], bF[4][2];
    int k0 = 64;
    #pragma unroll 1
    for (int t = 0; t < 15; ++t, k0 += 64) {
        const int cb = (t & 1) * 65536;            // consume buffer
        char* nDst = stDst + (65536 - cb);         // stage buffer (t+1)

        // ---- phase 1: quad(0,0); stage B q0,q1,q2 ----
        #pragma unroll
        for (int i = 0; i < 4; ++i) {
            aF[i][0] = *(const bf16x8*)(aRd + cb + i * 2048 + x0);
            aF[i][1] = *(const bf16x8*)(aRd + cb + i * 2048 + (x0 ^ 64));
        }
        #pragma unroll
        for (int j = 0; j < 2; ++j) {
            bF[j][0] = *(const bf16x8*)(bRd + cb + j * 2048 + x0);
            bF[j][1] = *(const bf16x8*)(bRd + cb + j * 2048 + (x0 ^ 64));
        }
        stageB3(bG, k0, nDst);
        BARRIER(); LGKM0();
        mma_quad<0, 0>(acc, aF, bF);
        BARRIER();

        // ---- phase 2: quad(0,1); stage B q3 + A.l1s; VMW(6) retires A.l2(t) ----
        #pragma unroll
        for (int j = 2; j < 4; ++j) {
            bF[j][0] = *(const bf16x8*)(bRd + cb + j * 2048 + x0);
            bF[j][1] = *(const bf16x8*)(bRd + cb + j * 2048 + (x0 ^ 64));
        }
        stageB1A2(bG, aG, k0, nDst);
        VMW(6);
        BARRIER(); LGKM0();
        mma_quad<0, 2>(acc, aF, bF);
        BARRIER();

        // ---- phase 3: quad(1,0); stage A.l2s ----
        #pragma unroll
        for (int i = 0; i < 4; ++i) {
            aF[i][0] = *(const bf16x8*)(aRd + cb + (4 + i) * 2048 + x0);
            aF[i][1] = *(const bf16x8*)(aRd + cb + (4 + i) * 2048 + (x0 ^ 64));
        }
        stageA2(aG, k0, nDst);
        BARRIER(); LGKM0();
        mma_quad<4, 0>(acc, aF, bF);
        BARRIER();

        // ---- phase 4: quad(1,1); VMW(2) retires what ph1(t+1) reads ----
        VMW(2);
        BARRIER();
        mma_quad<4, 2>(acc, aF, bF);
        BARRIER();
    }

    // ---- tail: K-tile 15 (buf1), no staging ----
    {
        const int cb = 65536;
        #pragma unroll
        for (int i = 0; i < 4; ++i) {
            aF[i][0] = *(const bf16x8*)(aRd + cb + i * 2048 + x0);
            aF[i][1] = *(const bf16x8*)(aRd + cb + i * 2048 + (x0 ^ 64));
        }
        #pragma unroll
        for (int j = 0; j < 2; ++j) {
            bF[j][0] = *(const bf16x8*)(bRd + cb + j * 2048 + x0);
            bF[j][1] = *(const bf16x8*)(bRd + cb + j * 2048 + (x0 ^ 64));
        }
        BARRIER(); LGKM0();
        mma_quad<0, 0>(acc, aF, bF);
        BARRIER();
        #pragma unroll
        for (int j = 2; j < 4; ++j) {
            bF[j][0] = *(const bf16x8*)(bRd + cb + j * 2048 + x0);
            bF[j][1] = *(const bf16x8*)(bRd + cb + j * 2048 + (x0 ^ 64));
        }
        VMW(0);   // retire A.l2(15) before the row-64..127 reads below
        BARRIER(); LGKM0();
        mma_quad<0, 2>(acc, aF, bF);
        BARRIER();
        #pragma unroll
        for (int i = 0; i < 4; ++i) {
            aF[i][0] = *(const bf16x8*)(aRd + cb + (4 + i) * 2048 + x0);
            aF[i][1] = *(const bf16x8*)(aRd + cb + (4 + i) * 2048 + (x0 ^ 64));
        }
        LGKM0();
        mma_quad<4, 0>(acc, aF, bF);
        mma_quad<4, 2>(acc, aF, bF);
    }
}

// ---------- GEMM1: [V|R] = X @ [Wv;Wr]^T, N=2048, sigmoid on R half ----------
__global__ __launch_bounds__(512, 2)
void gemm_vr(const u16* __restrict__ A, const u16* __restrict__ Wvr,
             u16* __restrict__ Vb, u16* __restrict__ Rb)
{
    __shared__ alignas(16) char smem[131072];
    const int wave = threadIdx.x >> 6;
    const int lane = threadIdx.x & 63;

    // bijective XCD swizzle: 512 blocks, 8 XCDs, 64 m-tiles x 8 n-tiles
    const int b    = blockIdx.x;
    const int xcd  = b & 7;
    const int sIdx = b >> 3;                 // 0..63
    const int mt   = xcd * 8 + (sIdx >> 3);  // 0..63
    const int nt   = sIdx & 7;               // 0..7
    const int m0   = mt * 256;
    const int n0   = nt * 256;

    const int l15 = lane & 15;
    const int g   = lane >> 4;
    const int wr  = wave >> 2;
    const int wc  = wave & 3;
    const int tid = wave * 64 + lane;

    const int srow = tid >> 3;
    const int kcol = ((tid & 7) ^ (srow & 7)) * 8;
    const u16* aG = A   + (size_t)(m0 + srow) * Cdim + kcol;
    const u16* bG = Wvr + (size_t)(n0 + srow) * Cdim + kcol;
    char* stDst = smem + wave * 1024;

    const int x0 = (g ^ (l15 & 7)) * 16;
    const char* aRd = smem + wr * 16384 + l15 * 128;
    const char* bRd = smem + 32768 + wc * 8192 + l15 * 128;

    f32x4 acc[8][4] = {};

    stage_full(aG, bG, stDst);
    VMW(2);
    BARRIER();
    kloop(aG, bG, stDst, aRd, bRd, x0, acc);

    const bool isR = (nt >= 4);
    u16* dst = isR ? Rb : Vb;
    const int cbase = n0 - (isR ? 1024 : 0) + (wave & 3) * 64 + l15;
    const int rbase = m0 + (wave >> 2) * 128 + g * 4;
    #pragma unroll
    for (int i = 0; i < 8; ++i)
        #pragma unroll
        for (int j = 0; j < 4; ++j)
            #pragma unroll
            for (int r = 0; r < 4; ++r) {
                float v = acc[i][j][r];
                if (isR) v = 1.f / (1.f + __expf(-v));
                dst[(size_t)(rbase + i * 16 + r) * Cdim + cbase + j * 16] = f2bf(v);
            }
}

// ---------- GEMM2: out = Y @ Wo^T, N=1024, fp32 out ----------
__global__ __launch_bounds__(512, 2)
void gemm_out(const u16* __restrict__ A, const u16* __restrict__ Wo,
              float* __restrict__ O)
{
    __shared__ alignas(16) char smem[131072];
    const int wave = threadIdx.x >> 6;
    const int lane = threadIdx.x & 63;

    const int b    = blockIdx.x;
    const int xcd  = b & 7;
    const int s    = b >> 3;                 // 0..31
    const int mt   = xcd * 8 + (s >> 2);     // 0..63
    const int nt   = s & 3;                  // 0..3
    const int m0   = mt * 256;

    const int l15 = lane & 15;
    const int g   = lane >> 4;
    const int wr  = wave >> 2;
    const int wc  = wave & 3;
    const int tid = wave * 64 + lane;

    const int srow = tid >> 3;
    const int kcol = ((tid & 7) ^ (srow & 7)) * 8;
    const u16* aG = A  + (size_t)(m0 + srow) * Cdim + kcol;
    const u16* bG = Wo + (size_t)(nt * 256 + srow) * Cdim + kcol;
    char* stDst = smem + wave * 1024;

    const int x0 = (g ^ (l15 & 7)) * 16;
    const char* aRd = smem + wr * 16384 + l15 * 128;
    const char* bRd = smem + 32768 + wc * 8192 + l15 * 128;

    f32x4 acc[8][4] = {};

    stage_full(aG, bG, stDst);
    VMW(2);
    BARRIER();
    kloop(aG, bG, stDst, aRd, bRd, x0, acc);

    const int cbase = nt * 256 + (wave & 3) * 64 + l15;
    const int rbase = m0 + (wave >> 2) * 128 + g * 4;
    #pragma unroll
    for (int i = 0; i < 8; ++i)
        #pragma unroll
        for (int j = 0; j < 4; ++j)
            #pragma unroll
            for (int r = 0; r < 4; ++r)
                O[(size_t)(rbase + i * 16 + r) * Cdim + cbase + j * 16] = acc[i][j][r];
}

// ---------- WKV fused: pass1 + grid.sync + pass2 in ONE cooperative kernel ----------
// 1024 blocks x 256 thr, 0 LDS, VGPR capped at 128 (launch_bounds 256,4)
// -> exactly 4 blocks/CU x 256 CUs = 1024 co-resident blocks.
__global__ __launch_bounds__(256, 4)
void wkv_fused(const u16* __restrict__ Vb, const u16* __restrict__ Rb,
               const float* __restrict__ td, const float* __restrict__ tf,
               float2* __restrict__ Sa, u16* __restrict__ Y)
{
    const int t = blockIdx.x * 256 + threadIdx.x;     // 0..262143
    const int cp    = t & (CP - 1);                   // 0..511
    const int chunk = (t >> 9) & (NCH - 1);           // 0..63
    const int b     = t >> 15;                        // 0..7

    const float2 tdc = *(const float2*)&td[cp * 2];
    const float lam0 = __expf(-fmaxf(tdc.x, 0.f)), mu0 = __expf(fminf(tdc.x, 0.f));
    const float lam1 = __expf(-fmaxf(tdc.y, 0.f)), mu1 = __expf(fminf(tdc.y, 0.f));

    const u32* V32 = (const u32*)Vb;
    const size_t base = ((size_t)(b * Tn + chunk * CLEN)) * CP + cp;

    // ---- phase 1: per-chunk decayed sums ----
    {
        size_t idx = base;
        float s0 = 0.f, s1 = 0.f;
        #pragma unroll 4
        for (int i = 0; i < CLEN; ++i, idx += CP) {
            const u32 vv = V32[idx];
            s0 = lam0 * s0 + mu0 * bf2f((u16)vv);
            s1 = lam1 * s1 + mu1 * bf2f((u16)(vv >> 16));
        }
        Sa[t] = make_float2(s0, s1);    // layout [b][chunk][cp] == t
    }

    cg::this_grid().sync();

    // ---- phase 2: cross-chunk prefix + output ----
    const float2 tfc = *(const float2*)&tf[cp * 2];
    const float e10  = __expf(-fmaxf(tfc.x, 0.f)), e20 = __expf(fminf(tfc.x, 0.f));
    const float e11  = __expf(-fmaxf(tfc.y, 0.f)), e21 = __expf(fminf(tfc.y, 0.f));
    const float lamL0 = __expf(-(float)CLEN * fmaxf(tdc.x, 0.f));
    const float lamL1 = __expf(-(float)CLEN * fmaxf(tdc.y, 0.f));
    const float Sb0 = (fabsf(1.f - lam0) < 1e-9f) ? mu0 * (float)CLEN
                                                  : mu0 * (1.f - lamL0) / (1.f - lam0);
    const float Sb1 = (fabsf(1.f - lam1) < 1e-9f) ? mu1 * (float)CLEN
                                                  : mu1 * (1.f - lamL1) / (1.f - lam1);

    float aa0 = 0.f, bb0 = 0.f, aa1 = 0.f, bb1 = 0.f;
    const float2* Sp = Sa + (size_t)b * (NCH * CP) + cp;
    #pragma unroll 4
    for (int j = 0; j < chunk; ++j) {
        const float2 s = Sp[(size_t)j * CP];
        aa0 = lamL0 * aa0 + s.x;  bb0 = lamL0 * bb0 + Sb0;
        aa1 = lamL1 * aa1 + s.y;  bb1 = lamL1 * bb1 + Sb1;
    }

    const u32* R32 = (const u32*)Rb;
    u32*       Y32 = (u32*)Y;
    size_t idx = base;
    #pragma unroll 4
    for (int i = 0; i < CLEN; ++i, idx += CP) {
        const u32 vv = V32[idx];
        const u32 rr = R32[idx];
        const float v0 = bf2f((u16)vv), v1 = bf2f((u16)(vv >> 16));
        const float r0 = bf2f((u16)rr), r1 = bf2f((u16)(rr >> 16));
        const float wkv0 = (e10 * aa0 + e20 * v0) *
                           __builtin_amdgcn_rcpf(e10 * bb0 + e20 + 1e-6f);
        const float wkv1 = (e11 * aa1 + e21 * v1) *
                           __builtin_amdgcn_rcpf(e11 * bb1 + e21 + 1e-6f);
        Y32[idx] = (u32)f2bf(r0 * wkv0) | ((u32)f2bf(r1 * wkv1) << 16);
        aa0 = lam0 * aa0 + mu0 * v0;  bb0 = lam0 * bb0 + mu0;
        aa1 = lam1 * aa1 + mu1 * v1;  bb1 = lam1 * bb1 + mu1;
    }
}

extern "C" void kernel_launch(void* const* d_in, const int* in_sizes, int n_in,
                              void* d_out, int out_size, void* d_ws, size_t ws_size,
                              hipStream_t stream)
{
    // inputs: x, time_decay, time_first, key_w(dead), value_w, recep_w, out_w
    const float* x       = (const float*)d_in[0];
    const float* td      = (const float*)d_in[1];
    const float* tf      = (const float*)d_in[2];
    const float* value_w = (const float*)d_in[4];
    const float* recep_w = (const float*)d_in[5];
    const float* out_w   = (const float*)d_in[6];
    float* out = (float*)d_out;

    char* ws = (char*)d_ws;
    const size_t MB = 1024 * 1024;
    u16*    Xb  = (u16*)(ws);               // 32 MB; reused as Yb after gemm_vr+wkv
    u16*    Vb  = (u16*)(ws + 32 * MB);     // 32 MB
    u16*    Rb  = (u16*)(ws + 64 * MB);     // 32 MB
    u16*    Wvr = (u16*)(ws + 96 * MB);     //  4 MB  (concat [Wv; Wr], 2048 x 1024)
    u16*    Wo  = (u16*)(ws + 100 * MB);    //  2 MB
    float2* Sa  = (float2*)(ws + 102 * MB); //  2 MB [8][64][512] float2
    u16*    Yb  = Xb;                       // alias: Xb dead after gemm_vr

    cast_all<<<19456, 256, 0, stream>>>(x, value_w, recep_w, out_w, Xb, Wvr, Wo);

    gemm_vr<<<512, 512, 0, stream>>>(Xb, Wvr, Vb, Rb);

    void* kargs[] = { (void*)&Vb, (void*)&Rb, (void*)&td, (void*)&tf,
                      (void*)&Sa, (void*)&Yb };
    hipLaunchCooperativeKernel((const void*)wkv_fused, dim3(Bn * NCH * CP / 256),
                               dim3(256), kargs, 0, stream);

    gemm_out<<<256, 512, 0, stream>>>(Yb, Wo, out);
}

// Round 8
// 268.019 us; speedup vs baseline: 1.3277x; 1.3277x over previous
//
#include <hip/hip_runtime.h>

using u16 = unsigned short;
using u32 = unsigned int;

// Problem constants: B=8, T=2048, C=1024
constexpr int Cdim  = 1024;
constexpr int Bn    = 8;
constexpr int Tn    = 2048;
constexpr int Mrows = Bn * Tn;          // 16384 rows in all GEMMs
constexpr int NCH   = 64;               // wkv chunks per chain
constexpr int CLEN  = Tn / NCH;         // 32 steps per chunk
constexpr int CP    = Cdim / 2;         // 512 channel-pairs

// ---------- bf16 helpers (bit-level, RNE) ----------
__device__ inline u16 f2bf(float x) {
    u32 u = __float_as_uint(x);
    u += 0x7fffu + ((u >> 16) & 1u);
    return (u16)(u >> 16);
}
__device__ inline float bf2f(u16 x) {
    return __uint_as_float(((u32)x) << 16);
}

// ---------- fp32 -> bf16 cast: X + 3 weights, ONE dispatch ----------
__global__ __launch_bounds__(256)
void cast_all(const float* __restrict__ x, const float* __restrict__ vw,
              const float* __restrict__ rw, const float* __restrict__ ow,
              u16* __restrict__ Xb, u16* __restrict__ Wvr, u16* __restrict__ Wo)
{
    const int b = blockIdx.x;
    const float4* src;
    ushort4*      dst;
    int i;
    if (b < 16384)      { src = (const float4*)x;  dst = (ushort4*)Xb;                i = b * 256 + threadIdx.x; }
    else if (b < 17408) { src = (const float4*)vw; dst = (ushort4*)Wvr;               i = (b - 16384) * 256 + threadIdx.x; }
    else if (b < 18432) { src = (const float4*)rw; dst = (ushort4*)(Wvr + 1048576);   i = (b - 17408) * 256 + threadIdx.x; }
    else                { src = (const float4*)ow; dst = (ushort4*)Wo;                i = (b - 18432) * 256 + threadIdx.x; }
    float4 v = src[i];
    ushort4 o;
    o.x = f2bf(v.x); o.y = f2bf(v.y); o.z = f2bf(v.z); o.w = f2bf(v.w);
    dst[i] = o;
}

// ---------- MFMA bf16 NT-GEMM, 256x256 tile, 8-phase pipelined ----------
typedef __bf16 bf16x8 __attribute__((ext_vector_type(8)));
typedef float  f32x4  __attribute__((ext_vector_type(4)));

#define SB0() __builtin_amdgcn_sched_barrier(0)
#define BARRIER() do { SB0(); __builtin_amdgcn_s_barrier(); SB0(); } while (0)
#define LGKM0()   do { asm volatile("s_waitcnt lgkmcnt(0)" ::: "memory"); SB0(); } while (0)
#define VMW(n)    do { asm volatile("s_waitcnt vmcnt(" #n ")" ::: "memory"); SB0(); } while (0)

__device__ __forceinline__ void gload16(const u16* g, char* l) {
    __builtin_amdgcn_global_load_lds(
        (const __attribute__((address_space(1))) void*)g,
        (__attribute__((address_space(3))) void*)l, 16, 0, 0);
}

// One C-quadrant x K=64: 16 MFMAs, setprio-wrapped (T5).
template<int IB, int JB>
__device__ __forceinline__ void mma_quad(f32x4 (&acc)[8][4],
                                         const bf16x8 (&aF)[4][2],
                                         const bf16x8 (&bF)[4][2]) {
    __builtin_amdgcn_s_setprio(1);
    #pragma unroll
    for (int i = 0; i < 4; ++i)
        #pragma unroll
        for (int j = 0; j < 2; ++j) {
            acc[IB + i][JB + j] = __builtin_amdgcn_mfma_f32_16x16x32_bf16(
                aF[i][0], bF[JB + j][0], acc[IB + i][JB + j], 0, 0, 0);
            acc[IB + i][JB + j] = __builtin_amdgcn_mfma_f32_16x16x32_bf16(
                aF[i][1], bF[JB + j][1], acc[IB + i][JB + j], 0, 0, 0);
        }
    __builtin_amdgcn_s_setprio(0);
}

// Staging order matches CONSUMPTION order (all B quarters + A.l1 needed at
// ph1, A.l2 at ph3). Per-tile issue: bq0,bq1,bq2 | bq3,a.h0l1,a.h1l1 |
// a.h0l2,a.h1l2 | (none). Waits: VMW(6) at ph2 retires A.l2(t) (3-phase
// cover); VMW(2) at ph4 retires the 6 loads ph1(t+1) reads (>=2-phase cover).
__device__ __forceinline__ void stageB3(const u16* bG, int k0, char* nDst) {
    gload16(bG + k0,              nDst + 32768);
    gload16(bG +  64 * Cdim + k0, nDst + 32768 + 8192);
    gload16(bG + 128 * Cdim + k0, nDst + 32768 + 16384);
}
__device__ __forceinline__ void stageB1A2(const u16* bG, const u16* aG, int k0, char* nDst) {
    gload16(bG + 192 * Cdim + k0, nDst + 32768 + 24576);
    gload16(aG + k0,              nDst);
    gload16(aG + 128 * Cdim + k0, nDst + 16384);
}
__device__ __forceinline__ void stageA2(const u16* aG, int k0, char* nDst) {
    gload16(aG +  64 * Cdim + k0, nDst + 8192);
    gload16(aG + 192 * Cdim + k0, nDst + 24576);
}
__device__ __forceinline__ void stage_full(const u16* aG, const u16* bG, char* dst) {
    stageB3(bG, 0, dst);
    stageB1A2(bG, aG, 0, dst);
    stageA2(aG, 0, dst);
}

// K-loop over 16 K-tiles (15 staged + tail). Caller must have issued
// stage_full into buf0 and executed VMW(2); BARRIER (a.l2 loads may remain
// in flight -- retired by ph2's VMW(6) at t=0).
__device__ __forceinline__ void kloop(const u16* __restrict__ aG,
                                      const u16* __restrict__ bG,
                                      char* stDst, const char* aRd,
                                      const char* bRd, int x0,
                                      f32x4 (&acc)[8][4])
{
    bf16x8 aF[4][2], bF[4][2];
    int k0 = 64;
    #pragma unroll 1
    for (int t = 0; t < 15; ++t, k0 += 64) {
        const int cb = (t & 1) * 65536;            // consume buffer
        char* nDst = stDst + (65536 - cb);         // stage buffer (t+1)

        // ---- phase 1: quad(0,0); stage B q0,q1,q2 ----
        #pragma unroll
        for (int i = 0; i < 4; ++i) {
            aF[i][0] = *(const bf16x8*)(aRd + cb + i * 2048 + x0);
            aF[i][1] = *(const bf16x8*)(aRd + cb + i * 2048 + (x0 ^ 64));
        }
        #pragma unroll
        for (int j = 0; j < 2; ++j) {
            bF[j][0] = *(const bf16x8*)(bRd + cb + j * 2048 + x0);
            bF[j][1] = *(const bf16x8*)(bRd + cb + j * 2048 + (x0 ^ 64));
        }
        stageB3(bG, k0, nDst);
        BARRIER(); LGKM0();
        mma_quad<0, 0>(acc, aF, bF);
        BARRIER();

        // ---- phase 2: quad(0,1); stage B q3 + A.l1s; VMW(6) retires A.l2(t) ----
        #pragma unroll
        for (int j = 2; j < 4; ++j) {
            bF[j][0] = *(const bf16x8*)(bRd + cb + j * 2048 + x0);
            bF[j][1] = *(const bf16x8*)(bRd + cb + j * 2048 + (x0 ^ 64));
        }
        stageB1A2(bG, aG, k0, nDst);
        VMW(6);
        BARRIER(); LGKM0();
        mma_quad<0, 2>(acc, aF, bF);
        BARRIER();

        // ---- phase 3: quad(1,0); stage A.l2s ----
        #pragma unroll
        for (int i = 0; i < 4; ++i) {
            aF[i][0] = *(const bf16x8*)(aRd + cb + (4 + i) * 2048 + x0);
            aF[i][1] = *(const bf16x8*)(aRd + cb + (4 + i) * 2048 + (x0 ^ 64));
        }
        stageA2(aG, k0, nDst);
        BARRIER(); LGKM0();
        mma_quad<4, 0>(acc, aF, bF);
        BARRIER();

        // ---- phase 4: quad(1,1); VMW(2) retires what ph1(t+1) reads ----
        VMW(2);
        BARRIER();
        mma_quad<4, 2>(acc, aF, bF);
        BARRIER();
    }

    // ---- tail: K-tile 15 (buf1), no staging ----
    {
        const int cb = 65536;
        #pragma unroll
        for (int i = 0; i < 4; ++i) {
            aF[i][0] = *(const bf16x8*)(aRd + cb + i * 2048 + x0);
            aF[i][1] = *(const bf16x8*)(aRd + cb + i * 2048 + (x0 ^ 64));
        }
        #pragma unroll
        for (int j = 0; j < 2; ++j) {
            bF[j][0] = *(const bf16x8*)(bRd + cb + j * 2048 + x0);
            bF[j][1] = *(const bf16x8*)(bRd + cb + j * 2048 + (x0 ^ 64));
        }
        BARRIER(); LGKM0();
        mma_quad<0, 0>(acc, aF, bF);
        BARRIER();
        #pragma unroll
        for (int j = 2; j < 4; ++j) {
            bF[j][0] = *(const bf16x8*)(bRd + cb + j * 2048 + x0);
            bF[j][1] = *(const bf16x8*)(bRd + cb + j * 2048 + (x0 ^ 64));
        }
        VMW(0);   // retire A.l2(15) before the row-64..127 reads below
        BARRIER(); LGKM0();
        mma_quad<0, 2>(acc, aF, bF);
        BARRIER();
        #pragma unroll
        for (int i = 0; i < 4; ++i) {
            aF[i][0] = *(const bf16x8*)(aRd + cb + (4 + i) * 2048 + x0);
            aF[i][1] = *(const bf16x8*)(aRd + cb + (4 + i) * 2048 + (x0 ^ 64));
        }
        LGKM0();
        mma_quad<4, 0>(acc, aF, bF);
        mma_quad<4, 2>(acc, aF, bF);
    }
}

// ---------- GEMM1: [V|R] = X @ [Wv;Wr]^T + fused wkv chunk-sums (pass1) ----------
// V-blocks additionally reduce their acc registers into Sa[b][chunk][c]:
// chunk-sum s = sum_k lam^(31-k) * mu * v_k over the 32 rows of each chunk.
// lam is uniform per column -> cross-lane composition is a weighted sum:
// in-lane Horner over r (4 rows), shfl_xor(16/32) combine across g (lam^4,
// lam^8 weights, order by g), then lam^16 combine across the i-pair.
__global__ __launch_bounds__(512, 2)
void gemm_vr(const u16* __restrict__ A, const u16* __restrict__ Wvr,
             const float* __restrict__ td,
             u16* __restrict__ Vb, u16* __restrict__ Rb, float* __restrict__ Sa)
{
    __shared__ alignas(16) char smem[131072];
    const int wave = threadIdx.x >> 6;
    const int lane = threadIdx.x & 63;

    // bijective XCD swizzle: 512 blocks, 8 XCDs, 64 m-tiles x 8 n-tiles
    const int b    = blockIdx.x;
    const int xcd  = b & 7;
    const int sIdx = b >> 3;                 // 0..63
    const int mt   = xcd * 8 + (sIdx >> 3);  // 0..63
    const int nt   = sIdx & 7;               // 0..7
    const int m0   = mt * 256;
    const int n0   = nt * 256;

    const int l15 = lane & 15;
    const int g   = lane >> 4;
    const int wr  = wave >> 2;
    const int wc  = wave & 3;
    const int tid = wave * 64 + lane;

    const int srow = tid >> 3;
    const int kcol = ((tid & 7) ^ (srow & 7)) * 8;
    const u16* aG = A   + (size_t)(m0 + srow) * Cdim + kcol;
    const u16* bG = Wvr + (size_t)(n0 + srow) * Cdim + kcol;
    char* stDst = smem + wave * 1024;

    const int x0 = (g ^ (l15 & 7)) * 16;
    const char* aRd = smem + wr * 16384 + l15 * 128;
    const char* bRd = smem + 32768 + wc * 8192 + l15 * 128;

    f32x4 acc[8][4] = {};

    stage_full(aG, bG, stDst);
    VMW(2);
    BARRIER();
    kloop(aG, bG, stDst, aRd, bRd, x0, acc);

    const bool isR = (nt >= 4);
    u16* dst = isR ? Rb : Vb;
    const int cbase = n0 - (isR ? 1024 : 0) + wc * 64 + l15;
    const int rbase = m0 + wr * 128 + g * 4;
    #pragma unroll
    for (int i = 0; i < 8; ++i)
        #pragma unroll
        for (int j = 0; j < 4; ++j)
            #pragma unroll
            for (int r = 0; r < 4; ++r) {
                float v = acc[i][j][r];
                if (isR) v = 1.f / (1.f + __expf(-v));
                dst[(size_t)(rbase + i * 16 + r) * Cdim + cbase + j * 16] = f2bf(v);
            }

    if (!isR) {
        // fused wkv_pass1: per-chunk decayed sums from registers.
        const int bidx   = mt >> 3;                       // batch
        const int chbase = (mt & 7) * 8 + wr * 4;         // + q -> chunk 0..63
        #pragma unroll
        for (int j = 0; j < 4; ++j) {
            const int c = cbase + j * 16;
            const float tdc  = td[c];
            const float lam  = __expf(-fmaxf(tdc, 0.f));
            const float mu   = __expf(fminf(tdc, 0.f));
            const float lam2 = lam * lam;
            const float lam4 = lam2 * lam2;
            const float lam8 = lam4 * lam4;
            const float lam16 = lam8 * lam8;
            #pragma unroll
            for (int q = 0; q < 4; ++q) {
                float P0, P1;
                {
                    const f32x4 v = acc[2 * q][j];
                    float s = mu * v[0];
                    s = __fmaf_rn(lam, s, mu * v[1]);
                    s = __fmaf_rn(lam, s, mu * v[2]);
                    s = __fmaf_rn(lam, s, mu * v[3]);
                    P0 = s;
                }
                {
                    const f32x4 v = acc[2 * q + 1][j];
                    float s = mu * v[0];
                    s = __fmaf_rn(lam, s, mu * v[1]);
                    s = __fmaf_rn(lam, s, mu * v[2]);
                    s = __fmaf_rn(lam, s, mu * v[3]);
                    P1 = s;
                }
                // combine across g (rows g*4 within each 16-row stripe)
                float o0 = __shfl_xor(P0, 16);
                float o1 = __shfl_xor(P1, 16);
                P0 = (g & 1) ? __fmaf_rn(lam4, o0, P0) : __fmaf_rn(lam4, P0, o0);
                P1 = (g & 1) ? __fmaf_rn(lam4, o1, P1) : __fmaf_rn(lam4, P1, o1);
                o0 = __shfl_xor(P0, 32);
                o1 = __shfl_xor(P1, 32);
                P0 = (g & 2) ? __fmaf_rn(lam8, o0, P0) : __fmaf_rn(lam8, P0, o0);
                P1 = (g & 2) ? __fmaf_rn(lam8, o1, P1) : __fmaf_rn(lam8, P1, o1);
                const float cs = __fmaf_rn(lam16, P0, P1);
                if (g == 0)
                    Sa[(size_t)bidx * (NCH * Cdim) +
                       (size_t)(chbase + q) * Cdim + c] = cs;
            }
        }
    }
}

// ---------- GEMM2: out = Y @ Wo^T, N=1024, fp32 out ----------
__global__ __launch_bounds__(512, 2)
void gemm_out(const u16* __restrict__ A, const u16* __restrict__ Wo,
              float* __restrict__ O)
{
    __shared__ alignas(16) char smem[131072];
    const int wave = threadIdx.x >> 6;
    const int lane = threadIdx.x & 63;

    const int b    = blockIdx.x;
    const int xcd  = b & 7;
    const int s    = b >> 3;                 // 0..31
    const int mt   = xcd * 8 + (s >> 2);     // 0..63
    const int nt   = s & 3;                  // 0..3
    const int m0   = mt * 256;

    const int l15 = lane & 15;
    const int g   = lane >> 4;
    const int wr  = wave >> 2;
    const int wc  = wave & 3;
    const int tid = wave * 64 + lane;

    const int srow = tid >> 3;
    const int kcol = ((tid & 7) ^ (srow & 7)) * 8;
    const u16* aG = A  + (size_t)(m0 + srow) * Cdim + kcol;
    const u16* bG = Wo + (size_t)(nt * 256 + srow) * Cdim + kcol;
    char* stDst = smem + wave * 1024;

    const int x0 = (g ^ (l15 & 7)) * 16;
    const char* aRd = smem + wr * 16384 + l15 * 128;
    const char* bRd = smem + 32768 + wc * 8192 + l15 * 128;

    f32x4 acc[8][4] = {};

    stage_full(aG, bG, stDst);
    VMW(2);
    BARRIER();
    kloop(aG, bG, stDst, aRd, bRd, x0, acc);

    const int cbase = nt * 256 + wc * 64 + l15;
    const int rbase = m0 + wr * 128 + g * 4;
    #pragma unroll
    for (int i = 0; i < 8; ++i)
        #pragma unroll
        for (int j = 0; j < 4; ++j)
            #pragma unroll
            for (int r = 0; r < 4; ++r)
                O[(size_t)(rbase + i * 16 + r) * Cdim + cbase + j * 16] = acc[i][j][r];
}

// ---------- WKV pass2: cross-chunk prefix + output ----------
__global__ __launch_bounds__(256)
void wkv_pass2(const u16* __restrict__ Vb, const u16* __restrict__ Rb,
               const float* __restrict__ td, const float* __restrict__ tf,
               const float2* __restrict__ Sa, u16* __restrict__ Y)
{
    const int t = blockIdx.x * 256 + threadIdx.x;
    const int cp    = t & (CP - 1);
    const int chunk = (t >> 9) & (NCH - 1);
    const int b     = t >> 15;

    const float2 tdc = *(const float2*)&td[cp * 2];
    const float2 tfc = *(const float2*)&tf[cp * 2];

    const float lam0 = __expf(-fmaxf(tdc.x, 0.f)), mu0 = __expf(fminf(tdc.x, 0.f));
    const float lam1 = __expf(-fmaxf(tdc.y, 0.f)), mu1 = __expf(fminf(tdc.y, 0.f));
    const float e10  = __expf(-fmaxf(tfc.x, 0.f)), e20 = __expf(fminf(tfc.x, 0.f));
    const float e11  = __expf(-fmaxf(tfc.y, 0.f)), e21 = __expf(fminf(tfc.y, 0.f));
    const float lamL0 = __expf(-(float)CLEN * fmaxf(tdc.x, 0.f));
    const float lamL1 = __expf(-(float)CLEN * fmaxf(tdc.y, 0.f));
    const float Sb0 = (fabsf(1.f - lam0) < 1e-9f) ? mu0 * (float)CLEN
                                                  : mu0 * (1.f - lamL0) / (1.f - lam0);
    const float Sb1 = (fabsf(1.f - lam1) < 1e-9f) ? mu1 * (float)CLEN
                                                  : mu1 * (1.f - lamL1) / (1.f - lam1);

    float aa0 = 0.f, bb0 = 0.f, aa1 = 0.f, bb1 = 0.f;
    const float2* Sp = Sa + (size_t)b * (NCH * CP) + cp;
    #pragma unroll 4
    for (int j = 0; j < chunk; ++j) {
        const float2 s = Sp[(size_t)j * CP];
        aa0 = lamL0 * aa0 + s.x;  bb0 = lamL0 * bb0 + Sb0;
        aa1 = lamL1 * aa1 + s.y;  bb1 = lamL1 * bb1 + Sb1;
    }

    const u32* V32 = (const u32*)Vb;
    const u32* R32 = (const u32*)Rb;
    u32*       Y32 = (u32*)Y;
    size_t idx = ((size_t)(b * Tn + chunk * CLEN)) * CP + cp;
    #pragma unroll 4
    for (int i = 0; i < CLEN; ++i, idx += CP) {
        const u32 vv = V32[idx];
        const u32 rr = R32[idx];
        const float v0 = bf2f((u16)vv), v1 = bf2f((u16)(vv >> 16));
        const float r0 = bf2f((u16)rr), r1 = bf2f((u16)(rr >> 16));
        const float wkv0 = (e10 * aa0 + e20 * v0) *
                           __builtin_amdgcn_rcpf(e10 * bb0 + e20 + 1e-6f);
        const float wkv1 = (e11 * aa1 + e21 * v1) *
                           __builtin_amdgcn_rcpf(e11 * bb1 + e21 + 1e-6f);
        Y32[idx] = (u32)f2bf(r0 * wkv0) | ((u32)f2bf(r1 * wkv1) << 16);
        aa0 = lam0 * aa0 + mu0 * v0;  bb0 = lam0 * bb0 + mu0;
        aa1 = lam1 * aa1 + mu1 * v1;  bb1 = lam1 * bb1 + mu1;
    }
}

extern "C" void kernel_launch(void* const* d_in, const int* in_sizes, int n_in,
                              void* d_out, int out_size, void* d_ws, size_t ws_size,
                              hipStream_t stream)
{
    // inputs: x, time_decay, time_first, key_w(dead), value_w, recep_w, out_w
    const float* x       = (const float*)d_in[0];
    const float* td      = (const float*)d_in[1];
    const float* tf      = (const float*)d_in[2];
    const float* value_w = (const float*)d_in[4];
    const float* recep_w = (const float*)d_in[5];
    const float* out_w   = (const float*)d_in[6];
    float* out = (float*)d_out;

    char* ws = (char*)d_ws;
    const size_t MB = 1024 * 1024;
    u16*    Xb  = (u16*)(ws);               // 32 MB; reused as Yb after gemm_vr+wkv
    u16*    Vb  = (u16*)(ws + 32 * MB);     // 32 MB
    u16*    Rb  = (u16*)(ws + 64 * MB);     // 32 MB
    u16*    Wvr = (u16*)(ws + 96 * MB);     //  4 MB  (concat [Wv; Wr], 2048 x 1024)
    u16*    Wo  = (u16*)(ws + 100 * MB);    //  2 MB
    float*  Sa  = (float*)(ws + 102 * MB);  //  2 MB [8][64][1024] float
    u16*    Yb  = Xb;                       // alias: Xb dead after gemm_vr

    cast_all<<<19456, 256, 0, stream>>>(x, value_w, recep_w, out_w, Xb, Wvr, Wo);

    gemm_vr<<<512, 512, 0, stream>>>(Xb, Wvr, td, Vb, Rb, Sa);

    const int nScan = Bn * NCH * CP;      // 262144 threads
    wkv_pass2<<<nScan / 256, 256, 0, stream>>>(Vb, Rb, td, tf, (const float2*)Sa, Yb);

    gemm_out<<<256, 512, 0, stream>>>(Yb, Wo, out);
}